// Round 9
// baseline (158.471 us; speedup 1.0000x reference)
//
#include <hip/hip_runtime.h>
#include <hip/hip_bf16.h>
#include <math.h>

// ShiftedWindowAttention 3D (Swin): 32^3, C=128, heads=4, hd=32, window 8^3
// (N=512), shift 4^3, 64 windows.
// Round 6 kernel, fourth submission (R6/R7/R8 benches were GPU-acquisition
// timeouts — no data, no edits):
// k_attn rewritten for the latency-bound diagnosis (R5: 61us, MfmaUtil 5%,
// VALUBusy 44%, Occ 20%): 64q/wave dual-stream, async-stage double-buffer
// w/ 1 barrier/chunk, exp2-space softmax, defer-max, bf16 bias table,
// mask-skip for interior windows.
// k_qkv/k_proj unchanged (fp16 MFMA, passed R5 at absmax 4.9e-4).
//
// ws layout (bytes):
//   qb  bf16 [256][512][32]  @ 0          (8,388,608)   q pre-scaled by hd^-.5*log2e
//   kb  bf16 [256][512][32]  @ 8388608
//   vb  bf16 [256][32][512]  @ 16777216   (V transposed per win-head)
//   ao  f16  [64*512][128]   @ 25165824   (8,388,608)
//   biasb bf16 [4][512][512] @ 33554432   (2,097,152)   pre-scaled by log2e
//   wq  f16  [384][128]      @ 35651584   (98,304)
//   wp  f16  [128][128]      @ 35749888   (32,768)

#define NTOT 262144

typedef float     f32x16 __attribute__((ext_vector_type(16)));
typedef __bf16    bf16x8 __attribute__((ext_vector_type(8)));
typedef _Float16  f16x8  __attribute__((ext_vector_type(8)));
typedef _Float16  f16x4  __attribute__((ext_vector_type(4)));
typedef unsigned int u32x4 __attribute__((ext_vector_type(4)));

__device__ __forceinline__ unsigned int pkbf16(float a, float b) {
  __hip_bfloat16 x = __float2bfloat16(a), y = __float2bfloat16(b);
  return (unsigned int)__builtin_bit_cast(unsigned short, x) |
         ((unsigned int)__builtin_bit_cast(unsigned short, y) << 16);
}
__device__ __forceinline__ unsigned short bfbits(float v) {
  return __builtin_bit_cast(unsigned short, __float2bfloat16(v));
}

// ------- bias precompute (bf16, log2e-scaled) + weight fp16 conversion -----
__global__ void k_bias(const float* __restrict__ rpb, const int* __restrict__ rpi,
                       unsigned short* __restrict__ biasb,
                       const float* __restrict__ qkvw, const float* __restrict__ projw,
                       _Float16* __restrict__ wq, _Float16* __restrict__ wp) {
  int idx = blockIdx.x * 256 + threadIdx.x;
  int t = rpi[idx];
  float4 b4 = *reinterpret_cast<const float4*>(rpb + 4 * t);
  const float L2E = 1.4426950408889634f;
  biasb[0 * NTOT + idx] = bfbits(b4.x * L2E);
  biasb[1 * NTOT + idx] = bfbits(b4.y * L2E);
  biasb[2 * NTOT + idx] = bfbits(b4.z * L2E);
  biasb[3 * NTOT + idx] = bfbits(b4.w * L2E);
  if (idx < 65536) {
    if (idx < 49152) wq[idx] = (_Float16)qkvw[idx];
    else             wp[idx - 49152] = (_Float16)projw[idx - 49152];
  }
}

// ------- fused roll + partition + QKV GEMM on fp16 MFMA --------------------
__global__ __launch_bounds__(256, 2) void k_qkv(
    const float* __restrict__ x, const _Float16* __restrict__ wq,
    const float* __restrict__ qkvb,
    __hip_bfloat16* __restrict__ qb, __hip_bfloat16* __restrict__ kb,
    __hip_bfloat16* __restrict__ vb) {
  __shared__ unsigned short As[128 * 128];
  __shared__ unsigned short Bs[128 * 128];
  const int tid = threadIdx.x;
  const int bm = blockIdx.x;
  const int nc = bm >> 8;              // 0=q 1=k 2=v
  const int mt = bm & 255;
  const int win = mt >> 2, t128 = mt & 3;
  const int wh = win >> 4, ww = (win >> 2) & 3, wd = win & 3;

#pragma unroll
  for (int u = 0; u < 8; ++u) {
    int f = u * 256 + tid;
    int row = f >> 4, seg = f & 15;
    int n = t128 * 128 + row;
    int lh = n >> 6, lw = (n >> 3) & 7, ld = n & 7;
    int sh = (wh * 8 + lh + 4) & 31;
    int sw = (ww * 8 + lw + 4) & 31;
    int sd = (wd * 8 + ld + 4) & 31;
    const float* src = x + ((sh * 32 + sw) * 32 + sd) * 128 + seg * 8;
    float4 a0 = *(const float4*)src;
    float4 a1 = *(const float4*)(src + 4);
    f16x8 hv;
    hv[0] = (_Float16)a0.x; hv[1] = (_Float16)a0.y;
    hv[2] = (_Float16)a0.z; hv[3] = (_Float16)a0.w;
    hv[4] = (_Float16)a1.x; hv[5] = (_Float16)a1.y;
    hv[6] = (_Float16)a1.z; hv[7] = (_Float16)a1.w;
    int slot = seg ^ (row & 15);
    *(u32x4*)(&As[row * 128 + slot * 8]) = __builtin_bit_cast(u32x4, hv);
  }
#pragma unroll
  for (int u = 0; u < 8; ++u) {
    int f = u * 256 + tid;
    int row = f >> 4, seg = f & 15;
    u32x4 wv = *(const u32x4*)(wq + (nc * 128 + row) * 128 + seg * 8);
    int slot = seg ^ (row & 15);
    *(u32x4*)(&Bs[row * 128 + slot * 8]) = wv;
  }
  __syncthreads();

  const int wave = tid >> 6, lane = tid & 63;
  const int lq = lane & 31, h = lane >> 5;
  const int wm = wave >> 1, wn = wave & 1;

  f32x16 a00, a01, a10, a11;
#pragma unroll
  for (int r = 0; r < 16; ++r) { a00[r] = 0.f; a01[r] = 0.f; a10[r] = 0.f; a11[r] = 0.f; }

#pragma unroll
  for (int ks = 0; ks < 8; ++ks) {
    int r0 = wm * 64 + lq, r1 = wm * 64 + 32 + lq;
    int c0 = wn * 64 + lq, c1 = wn * 64 + 32 + lq;
    int sl = ks * 2 + h;
    f16x8 af0 = __builtin_bit_cast(f16x8, *(const u32x4*)(&As[r0 * 128 + (sl ^ (r0 & 15)) * 8]));
    f16x8 af1 = __builtin_bit_cast(f16x8, *(const u32x4*)(&As[r1 * 128 + (sl ^ (r1 & 15)) * 8]));
    f16x8 bf0 = __builtin_bit_cast(f16x8, *(const u32x4*)(&Bs[c0 * 128 + (sl ^ (c0 & 15)) * 8]));
    f16x8 bf1 = __builtin_bit_cast(f16x8, *(const u32x4*)(&Bs[c1 * 128 + (sl ^ (c1 & 15)) * 8]));
    a00 = __builtin_amdgcn_mfma_f32_32x32x16_f16(af0, bf0, a00, 0, 0, 0);
    a01 = __builtin_amdgcn_mfma_f32_32x32x16_f16(af0, bf1, a01, 0, 0, 0);
    a10 = __builtin_amdgcn_mfma_f32_32x32x16_f16(af1, bf0, a10, 0, 0, 0);
    a11 = __builtin_amdgcn_mfma_f32_32x32x16_f16(af1, bf1, a11, 0, 0, 0);
  }

  // q scale now folds log2e for the exp2-space softmax in k_attn
  const float scale = (float)(0.17677669529663687 * 1.4426950408889634);
  float bias0 = qkvb[nc * 128 + wn * 64 + lq];
  float bias1 = qkvb[nc * 128 + wn * 64 + 32 + lq];

#define EPI_QK(ACC, MI, NI, DST, DO_SCALE)                                    \
  {                                                                           \
    int head = wn * 2 + (NI);                                                 \
    size_t whb = (size_t)(win * 4 + head);                                    \
    float bc = (NI) ? bias1 : bias0;                                          \
    _Pragma("unroll")                                                         \
    for (int r = 0; r < 16; ++r) {                                            \
      int row32 = (r & 3) + 8 * (r >> 2) + 4 * h;                             \
      int n = t128 * 128 + wm * 64 + (MI) * 32 + row32;                       \
      float val = ACC[r] + bc;                                                \
      if (DO_SCALE) val *= scale;                                             \
      DST[(whb * 512 + n) * 32 + lq] = __float2bfloat16(val);                 \
    }                                                                         \
  }
#define EPI_V(ACC, MI, NI)                                                    \
  {                                                                           \
    int head = wn * 2 + (NI);                                                 \
    size_t whb = (size_t)(win * 4 + head);                                    \
    float bc = (NI) ? bias1 : bias0;                                          \
    _Pragma("unroll")                                                         \
    for (int g = 0; g < 4; ++g) {                                             \
      int n0 = t128 * 128 + wm * 64 + (MI) * 32 + g * 8 + 4 * h;              \
      uint2 u = make_uint2(pkbf16(ACC[g * 4 + 0] + bc, ACC[g * 4 + 1] + bc),  \
                           pkbf16(ACC[g * 4 + 2] + bc, ACC[g * 4 + 3] + bc)); \
      *(uint2*)(vb + (whb * 32 + lq) * 512 + n0) = u;                         \
    }                                                                         \
  }

  if (nc == 0) {
    EPI_QK(a00, 0, 0, qb, 1); EPI_QK(a01, 0, 1, qb, 1);
    EPI_QK(a10, 1, 0, qb, 1); EPI_QK(a11, 1, 1, qb, 1);
  } else if (nc == 1) {
    EPI_QK(a00, 0, 0, kb, 0); EPI_QK(a01, 0, 1, kb, 0);
    EPI_QK(a10, 1, 0, kb, 0); EPI_QK(a11, 1, 1, kb, 0);
  } else {
    EPI_V(a00, 0, 0); EPI_V(a01, 0, 1);
    EPI_V(a10, 1, 0); EPI_V(a11, 1, 1);
  }
}

// ------- attention: dual-stream (64q/wave), async dbuf, exp2 softmax -------
// grid 512 = 64 win * 4 head * 2 half; block 256 (4 waves). Each wave owns
// queries [half*256 + wave*64, +64): stream A = first 32, stream B = next 32.
__global__ __launch_bounds__(256) void k_attn(
    const __hip_bfloat16* __restrict__ qb, const __hip_bfloat16* __restrict__ kb,
    const __hip_bfloat16* __restrict__ vb, const unsigned short* __restrict__ biasb,
    _Float16* __restrict__ ao) {
  __shared__ unsigned short Ks[2][64 * 40];   // keys x 32ch, 80B rows
  __shared__ unsigned short Vs[2][32 * 72];   // d x 64 keys, 144B rows
  __shared__ unsigned char regid[512];

  const int tid = threadIdx.x;
  const int b = blockIdx.x;
  const int win = b >> 3, head = (b >> 1) & 3, half = b & 1;
  const int wh = win >> 4, ww = (win >> 2) & 3, wd = win & 3;
  const int wave = tid >> 6, lane = tid & 63;
  const int lq = lane & 31, h = lane >> 5;
  const int qA = half * 256 + wave * 64 + lq;
  const int qB = qA + 32;
  const bool has_mask = (wh == 3) || (ww == 3) || (wd == 3);

  unsigned rnA = 0, rnB = 0;
  if (has_mask) {
#pragma unroll
    for (int i = 0; i < 2; ++i) {
      int n = tid + i * 256;
      int lh = n >> 6, lw = (n >> 3) & 7, ld = n & 7;
      regid[n] = (unsigned char)(((wh == 3) ? (lh < 4 ? 1 : 2) : 0) * 9 +
                                 ((ww == 3) ? (lw < 4 ? 1 : 2) : 0) * 3 +
                                 ((wd == 3) ? (ld < 4 ? 1 : 2) : 0));
    }
    {
      int n = qA;
      int lh = n >> 6, lw = (n >> 3) & 7, ld = n & 7;
      rnA = (unsigned)(((wh == 3) ? (lh < 4 ? 1 : 2) : 0) * 9 +
                       ((ww == 3) ? (lw < 4 ? 1 : 2) : 0) * 3 +
                       ((wd == 3) ? (ld < 4 ? 1 : 2) : 0));
      n = qB; lh = n >> 6; lw = (n >> 3) & 7; ld = n & 7;
      rnB = (unsigned)(((wh == 3) ? (lh < 4 ? 1 : 2) : 0) * 9 +
                       ((ww == 3) ? (lw < 4 ? 1 : 2) : 0) * 3 +
                       ((wd == 3) ? (ld < 4 ? 1 : 2) : 0));
    }
  }

  const size_t whb = (size_t)(win * 4 + head);
  const __hip_bfloat16* qrowA = qb + (whb * 512 + qA) * 32;
  const __hip_bfloat16* qrowB = qb + (whb * 512 + qB) * 32;
  bf16x8 qfA0 = __builtin_bit_cast(bf16x8, *(const u32x4*)(qrowA + h * 8));
  bf16x8 qfA1 = __builtin_bit_cast(bf16x8, *(const u32x4*)(qrowA + 16 + h * 8));
  bf16x8 qfB0 = __builtin_bit_cast(bf16x8, *(const u32x4*)(qrowB + h * 8));
  bf16x8 qfB1 = __builtin_bit_cast(bf16x8, *(const u32x4*)(qrowB + 16 + h * 8));

  const __hip_bfloat16* kg = kb + whb * 512 * 32;
  const __hip_bfloat16* vg = vb + whb * 32 * 512;
  const unsigned short* browA = biasb + ((size_t)head * 512 + qA) * 512;
  const unsigned short* browB = biasb + ((size_t)head * 512 + qB) * 512;

  float mA = -3.0e38f, lA = 0.f, mB = -3.0e38f, lB = 0.f;
  f32x16 oA, oB;
#pragma unroll
  for (int r = 0; r < 16; ++r) { oA[r] = 0.f; oB[r] = 0.f; }

  // async staging: global->reg early, reg->LDS late (T14)
  const int srow = tid >> 2, sseg = tid & 3;
  const int svd = tid >> 3, sseg2 = tid & 7;
  u32x4 kreg, vreg;
#define GLOAD(CHK)                                                            \
  { kreg = *(const u32x4*)(kg + ((CHK) * 64 + srow) * 32 + sseg * 8);         \
    vreg = *(const u32x4*)(vg + svd * 512 + (CHK) * 64 + sseg2 * 8); }
#define LWRITE(BUF)                                                           \
  { *(u32x4*)(&Ks[BUF][srow * 40 + sseg * 8]) = kreg;                         \
    *(u32x4*)(&Vs[BUF][svd * 72 + sseg2 * 8]) = vreg; }

  GLOAD(0); LWRITE(0);
  __syncthreads();

  // one softmax+PV stream (32 queries) over a 32-key subtile
  auto stream_step = [&](f32x16 c, float& m_run, float& l_run, f32x16& o,
                         const unsigned short* brow, unsigned rn,
                         bf16x8 vf0, bf16x8 vf1, int kbase) {
    float s[16];
#pragma unroll
    for (int j = 0; j < 4; ++j) {
      uint2 bb = *(const uint2*)(brow + kbase + h * 4 + j * 8);
      float b0 = __uint_as_float(bb.x << 16);
      float b1 = __uint_as_float(bb.x & 0xFFFF0000u);
      float b2 = __uint_as_float(bb.y << 16);
      float b3 = __uint_as_float(bb.y & 0xFFFF0000u);
      if (has_mask) {
        unsigned rm = *(const unsigned*)(&regid[kbase + h * 4 + j * 8]);
        b0 += ((rm & 255u) == rn) ? 0.f : -144.2695041f;
        b1 += (((rm >> 8) & 255u) == rn) ? 0.f : -144.2695041f;
        b2 += (((rm >> 16) & 255u) == rn) ? 0.f : -144.2695041f;
        b3 += (((rm >> 24)) == rn) ? 0.f : -144.2695041f;
      }
      s[j * 4 + 0] = c[j * 4 + 0] + b0;
      s[j * 4 + 1] = c[j * 4 + 1] + b1;
      s[j * 4 + 2] = c[j * 4 + 2] + b2;
      s[j * 4 + 3] = c[j * 4 + 3] + b3;
    }
    // tree max (depth 4)
    float x0 = fmaxf(s[0], s[8]),  x1 = fmaxf(s[1], s[9]);
    float x2 = fmaxf(s[2], s[10]), x3 = fmaxf(s[3], s[11]);
    float x4 = fmaxf(s[4], s[12]), x5 = fmaxf(s[5], s[13]);
    float x6 = fmaxf(s[6], s[14]), x7 = fmaxf(s[7], s[15]);
    x0 = fmaxf(x0, x4); x1 = fmaxf(x1, x5); x2 = fmaxf(x2, x6); x3 = fmaxf(x3, x7);
    x0 = fmaxf(x0, x2); x1 = fmaxf(x1, x3);
    float tmax = fmaxf(x0, x1);
    tmax = fmaxf(tmax, __shfl_xor(tmax, 32, 64));
    // defer-max: only rescale when the running max grew by >8 nats (11.54 log2)
    if (!__all(tmax <= m_run + 11.5415603f)) {
      float mn = fmaxf(m_run, tmax);
      float alpha = exp2f(m_run - mn);
      l_run *= alpha;
#pragma unroll
      for (int r = 0; r < 16; ++r) o[r] *= alpha;
      m_run = mn;
    }
    float p[16], lsum = 0.f;
#pragma unroll
    for (int r = 0; r < 16; ++r) { p[r] = exp2f(s[r] - m_run); lsum += p[r]; }
    lsum += __shfl_xor(lsum, 32, 64);
    l_run += lsum;
    unsigned bw[8];
#pragma unroll
    for (int g = 0; g < 8; ++g) bw[g] = pkbf16(p[2 * g], p[2 * g + 1]);
#pragma unroll
    for (int kc = 0; kc < 2; ++kc) {
      unsigned b0 = bw[kc * 4 + 0], b1 = bw[kc * 4 + 1];
      unsigned b2 = bw[kc * 4 + 2], b3 = bw[kc * 4 + 3];
      unsigned sb0 = __shfl_xor(b0, 32, 64), sb1 = __shfl_xor(b1, 32, 64);
      unsigned sb2 = __shfl_xor(b2, 32, 64), sb3 = __shfl_xor(b3, 32, 64);
      u32x4 pw;
      pw.x = h ? sb2 : b0;
      pw.y = h ? sb3 : b1;
      pw.z = h ? b2 : sb0;
      pw.w = h ? b3 : sb1;
      bf16x8 pf = __builtin_bit_cast(bf16x8, pw);
      o = __builtin_amdgcn_mfma_f32_32x32x16_bf16(kc ? vf1 : vf0, pf, o, 0, 0, 0);
    }
  };

  for (int chk = 0; chk < 8; ++chk) {
    const int cur = chk & 1;
    if (chk < 7) GLOAD(chk + 1);           // issue next-tile loads (hide under compute)

#pragma unroll
    for (int sub = 0; sub < 2; ++sub) {
      const int kbase = chk * 64 + sub * 32;
      const unsigned short* KsC = Ks[cur];
      const unsigned short* VsC = Vs[cur];
      bf16x8 kf0 = __builtin_bit_cast(bf16x8, *(const u32x4*)(&KsC[(sub * 32 + lq) * 40 + h * 8]));
      bf16x8 kf1 = __builtin_bit_cast(bf16x8, *(const u32x4*)(&KsC[(sub * 32 + lq) * 40 + 16 + h * 8]));
      f32x16 cA, cB;
#pragma unroll
      for (int r = 0; r < 16; ++r) { cA[r] = 0.f; cB[r] = 0.f; }
      cA = __builtin_amdgcn_mfma_f32_32x32x16_bf16(kf0, qfA0, cA, 0, 0, 0);
      cA = __builtin_amdgcn_mfma_f32_32x32x16_bf16(kf1, qfA1, cA, 0, 0, 0);
      cB = __builtin_amdgcn_mfma_f32_32x32x16_bf16(kf0, qfB0, cB, 0, 0, 0);
      cB = __builtin_amdgcn_mfma_f32_32x32x16_bf16(kf1, qfB1, cB, 0, 0, 0);
      bf16x8 vf0 = __builtin_bit_cast(bf16x8, *(const u32x4*)(&VsC[lq * 72 + sub * 32 + h * 8]));
      bf16x8 vf1 = __builtin_bit_cast(bf16x8, *(const u32x4*)(&VsC[lq * 72 + sub * 32 + 16 + h * 8]));
      stream_step(cA, mA, lA, oA, browA, rnA, vf0, vf1, kbase);
      stream_step(cB, mB, lB, oB, browB, rnB, vf0, vf1, kbase);
    }

    if (chk < 7) LWRITE(cur ^ 1);          // reg->LDS after compute (prev readers barrier-separated)
    __syncthreads();
  }

  const float invA = 1.f / lA, invB = 1.f / lB;
  _Float16* orowA = ao + ((size_t)(win * 512 + qA)) * 128 + head * 32;
  _Float16* orowB = ao + ((size_t)(win * 512 + qB)) * 128 + head * 32;
#pragma unroll
  for (int j = 0; j < 4; ++j) {
    int d0 = j * 8 + h * 4;
    f16x4 tA, tB;
    tA[0] = (_Float16)(oA[j * 4 + 0] * invA); tA[1] = (_Float16)(oA[j * 4 + 1] * invA);
    tA[2] = (_Float16)(oA[j * 4 + 2] * invA); tA[3] = (_Float16)(oA[j * 4 + 3] * invA);
    tB[0] = (_Float16)(oB[j * 4 + 0] * invB); tB[1] = (_Float16)(oB[j * 4 + 1] * invB);
    tB[2] = (_Float16)(oB[j * 4 + 2] * invB); tB[3] = (_Float16)(oB[j * 4 + 3] * invB);
    *(f16x4*)(orowA + d0) = tA;
    *(f16x4*)(orowB + d0) = tB;
  }
}

// ------- proj GEMM (fp16 MFMA) + reverse partition + reverse roll ----------
__global__ __launch_bounds__(256, 2) void k_proj(
    const _Float16* __restrict__ ao, const _Float16* __restrict__ wp,
    const float* __restrict__ pb, float* __restrict__ out) {
  __shared__ unsigned short As[128 * 128];
  __shared__ unsigned short Bs[128 * 128];
  const int tid = threadIdx.x;
  const int mt = blockIdx.x;
  const int win = mt >> 2, t128 = mt & 3;
  const int wh = win >> 4, ww = (win >> 2) & 3, wd = win & 3;

#pragma unroll
  for (int u = 0; u < 8; ++u) {
    int f = u * 256 + tid;
    int row = f >> 4, seg = f & 15;
    u32x4 av = *(const u32x4*)(ao + ((size_t)(win * 512 + t128 * 128 + row)) * 128 + seg * 8);
    int slot = seg ^ (row & 15);
    *(u32x4*)(&As[row * 128 + slot * 8]) = av;
  }
#pragma unroll
  for (int u = 0; u < 8; ++u) {
    int f = u * 256 + tid;
    int row = f >> 4, seg = f & 15;
    u32x4 wv = *(const u32x4*)(wp + row * 128 + seg * 8);
    int slot = seg ^ (row & 15);
    *(u32x4*)(&Bs[row * 128 + slot * 8]) = wv;
  }
  __syncthreads();

  const int wave = tid >> 6, lane = tid & 63;
  const int lq = lane & 31, h = lane >> 5;
  const int wm = wave >> 1, wn = wave & 1;

  f32x16 a00, a01, a10, a11;
#pragma unroll
  for (int r = 0; r < 16; ++r) { a00[r] = 0.f; a01[r] = 0.f; a10[r] = 0.f; a11[r] = 0.f; }

#pragma unroll
  for (int ks = 0; ks < 8; ++ks) {
    int r0 = wm * 64 + lq, r1 = wm * 64 + 32 + lq;
    int c0 = wn * 64 + lq, c1 = wn * 64 + 32 + lq;
    int sl = ks * 2 + h;
    f16x8 af0 = __builtin_bit_cast(f16x8, *(const u32x4*)(&As[r0 * 128 + (sl ^ (r0 & 15)) * 8]));
    f16x8 af1 = __builtin_bit_cast(f16x8, *(const u32x4*)(&As[r1 * 128 + (sl ^ (r1 & 15)) * 8]));
    f16x8 bf0 = __builtin_bit_cast(f16x8, *(const u32x4*)(&Bs[c0 * 128 + (sl ^ (c0 & 15)) * 8]));
    f16x8 bf1 = __builtin_bit_cast(f16x8, *(const u32x4*)(&Bs[c1 * 128 + (sl ^ (c1 & 15)) * 8]));
    a00 = __builtin_amdgcn_mfma_f32_32x32x16_f16(af0, bf0, a00, 0, 0, 0);
    a01 = __builtin_amdgcn_mfma_f32_32x32x16_f16(af0, bf1, a01, 0, 0, 0);
    a10 = __builtin_amdgcn_mfma_f32_32x32x16_f16(af1, bf0, a10, 0, 0, 0);
    a11 = __builtin_amdgcn_mfma_f32_32x32x16_f16(af1, bf1, a11, 0, 0, 0);
  }

  float bias0 = pb[wn * 64 + lq];
  float bias1 = pb[wn * 64 + 32 + lq];

#define EPI_P(ACC, MI, NI)                                                    \
  {                                                                           \
    int col = wn * 64 + (NI) * 32 + lq;                                       \
    float bc = (NI) ? bias1 : bias0;                                          \
    _Pragma("unroll")                                                         \
    for (int r = 0; r < 16; ++r) {                                            \
      int row32 = (r & 3) + 8 * (r >> 2) + 4 * h;                             \
      int n = t128 * 128 + wm * 64 + (MI) * 32 + row32;                       \
      int lh = n >> 6, lw = (n >> 3) & 7, ld = n & 7;                         \
      int dh = (wh * 8 + lh + 4) & 31;                                        \
      int dw = (ww * 8 + lw + 4) & 31;                                        \
      int dd = (wd * 8 + ld + 4) & 31;                                        \
      out[(size_t)((dh * 32 + dw) * 32 + dd) * 128 + col] = ACC[r] + bc;      \
    }                                                                         \
  }
  EPI_P(a00, 0, 0); EPI_P(a01, 0, 1); EPI_P(a10, 1, 0); EPI_P(a11, 1, 1);
}

extern "C" void kernel_launch(void* const* d_in, const int* in_sizes, int n_in,
                              void* d_out, int out_size, void* d_ws, size_t ws_size,
                              hipStream_t stream) {
  const float* x    = (const float*)d_in[0];
  const float* qkvw = (const float*)d_in[1];
  const float* qkvb = (const float*)d_in[2];
  const float* pw   = (const float*)d_in[3];
  const float* pb   = (const float*)d_in[4];
  const float* rpb  = (const float*)d_in[5];
  const int*   rpi  = (const int*)d_in[6];
  float* out = (float*)d_out;

  char* base = (char*)d_ws;
  __hip_bfloat16* qbuf = (__hip_bfloat16*)(base);
  __hip_bfloat16* kbuf = (__hip_bfloat16*)(base + 8388608);
  __hip_bfloat16* vbuf = (__hip_bfloat16*)(base + 16777216);
  _Float16* ao = (_Float16*)(base + 25165824);
  unsigned short* biasb = (unsigned short*)(base + 33554432);
  _Float16* wq = (_Float16*)(base + 35651584);
  _Float16* wp = (_Float16*)(base + 35749888);

  hipLaunchKernelGGL(k_bias, dim3(1024), dim3(256), 0, stream, rpb, rpi, biasb, qkvw, pw, wq, wp);
  hipLaunchKernelGGL(k_qkv,  dim3(768),  dim3(256), 0, stream, x, wq, qkvb, qbuf, kbuf, vbuf);
  hipLaunchKernelGGL(k_attn, dim3(512),  dim3(256), 0, stream, qbuf, kbuf, vbuf, biasb, ao);
  hipLaunchKernelGGL(k_proj, dim3(256),  dim3(256), 0, stream, ao, wp, pb, out);
}

// Round 10
// 155.595 us; speedup vs baseline: 1.0185x; 1.0185x over previous
//
#include <hip/hip_runtime.h>
#include <hip/hip_bf16.h>
#include <math.h>

// ShiftedWindowAttention 3D (Swin): 32^3, C=128, heads=4, hd=32, window 8^3
// (N=512), shift 4^3, 64 windows.
// Round 9: FIXED-MAX softmax in k_attn. R9 post-mortem: dual-stream kept
// per-wave VALU volume as the binding constraint (64.5us, VALU 46% @ 2
// waves/SIMD). Scores are bounded => softmax needs no running max at all:
// p = exp2(s) raw (shift-invariance; masked s=-144 -> p=0 exactly).
// Removes max-tree, max-shfl, __all, rescale, per-sub l-shfl. Bias loads
// prefetched before QK MFMAs. k_qkv/k_proj/k_bias unchanged.
//
// ws layout (bytes):
//   qb  bf16 [256][512][32]  @ 0          (8,388,608)   q pre-scaled by hd^-.5*log2e
//   kb  bf16 [256][512][32]  @ 8388608
//   vb  bf16 [256][32][512]  @ 16777216   (V transposed per win-head)
//   ao  f16  [64*512][128]   @ 25165824   (8,388,608)
//   biasb bf16 [4][512][512] @ 33554432   (2,097,152)   pre-scaled by log2e
//   wq  f16  [384][128]      @ 35651584   (98,304)
//   wp  f16  [128][128]      @ 35749888   (32,768)

#define NTOT 262144

typedef float     f32x16 __attribute__((ext_vector_type(16)));
typedef __bf16    bf16x8 __attribute__((ext_vector_type(8)));
typedef _Float16  f16x8  __attribute__((ext_vector_type(8)));
typedef _Float16  f16x4  __attribute__((ext_vector_type(4)));
typedef unsigned int u32x4 __attribute__((ext_vector_type(4)));

__device__ __forceinline__ unsigned int pkbf16(float a, float b) {
  __hip_bfloat16 x = __float2bfloat16(a), y = __float2bfloat16(b);
  return (unsigned int)__builtin_bit_cast(unsigned short, x) |
         ((unsigned int)__builtin_bit_cast(unsigned short, y) << 16);
}
__device__ __forceinline__ unsigned short bfbits(float v) {
  return __builtin_bit_cast(unsigned short, __float2bfloat16(v));
}

// ------- bias precompute (bf16, log2e-scaled) + weight fp16 conversion -----
__global__ void k_bias(const float* __restrict__ rpb, const int* __restrict__ rpi,
                       unsigned short* __restrict__ biasb,
                       const float* __restrict__ qkvw, const float* __restrict__ projw,
                       _Float16* __restrict__ wq, _Float16* __restrict__ wp) {
  int idx = blockIdx.x * 256 + threadIdx.x;
  int t = rpi[idx];
  float4 b4 = *reinterpret_cast<const float4*>(rpb + 4 * t);
  const float L2E = 1.4426950408889634f;
  biasb[0 * NTOT + idx] = bfbits(b4.x * L2E);
  biasb[1 * NTOT + idx] = bfbits(b4.y * L2E);
  biasb[2 * NTOT + idx] = bfbits(b4.z * L2E);
  biasb[3 * NTOT + idx] = bfbits(b4.w * L2E);
  if (idx < 65536) {
    if (idx < 49152) wq[idx] = (_Float16)qkvw[idx];
    else             wp[idx - 49152] = (_Float16)projw[idx - 49152];
  }
}

// ------- fused roll + partition + QKV GEMM on fp16 MFMA --------------------
__global__ __launch_bounds__(256, 2) void k_qkv(
    const float* __restrict__ x, const _Float16* __restrict__ wq,
    const float* __restrict__ qkvb,
    __hip_bfloat16* __restrict__ qb, __hip_bfloat16* __restrict__ kb,
    __hip_bfloat16* __restrict__ vb) {
  __shared__ unsigned short As[128 * 128];
  __shared__ unsigned short Bs[128 * 128];
  const int tid = threadIdx.x;
  const int bm = blockIdx.x;
  const int nc = bm >> 8;              // 0=q 1=k 2=v
  const int mt = bm & 255;
  const int win = mt >> 2, t128 = mt & 3;
  const int wh = win >> 4, ww = (win >> 2) & 3, wd = win & 3;

#pragma unroll
  for (int u = 0; u < 8; ++u) {
    int f = u * 256 + tid;
    int row = f >> 4, seg = f & 15;
    int n = t128 * 128 + row;
    int lh = n >> 6, lw = (n >> 3) & 7, ld = n & 7;
    int sh = (wh * 8 + lh + 4) & 31;
    int sw = (ww * 8 + lw + 4) & 31;
    int sd = (wd * 8 + ld + 4) & 31;
    const float* src = x + ((sh * 32 + sw) * 32 + sd) * 128 + seg * 8;
    float4 a0 = *(const float4*)src;
    float4 a1 = *(const float4*)(src + 4);
    f16x8 hv;
    hv[0] = (_Float16)a0.x; hv[1] = (_Float16)a0.y;
    hv[2] = (_Float16)a0.z; hv[3] = (_Float16)a0.w;
    hv[4] = (_Float16)a1.x; hv[5] = (_Float16)a1.y;
    hv[6] = (_Float16)a1.z; hv[7] = (_Float16)a1.w;
    int slot = seg ^ (row & 15);
    *(u32x4*)(&As[row * 128 + slot * 8]) = __builtin_bit_cast(u32x4, hv);
  }
#pragma unroll
  for (int u = 0; u < 8; ++u) {
    int f = u * 256 + tid;
    int row = f >> 4, seg = f & 15;
    u32x4 wv = *(const u32x4*)(wq + (nc * 128 + row) * 128 + seg * 8);
    int slot = seg ^ (row & 15);
    *(u32x4*)(&Bs[row * 128 + slot * 8]) = wv;
  }
  __syncthreads();

  const int wave = tid >> 6, lane = tid & 63;
  const int lq = lane & 31, h = lane >> 5;
  const int wm = wave >> 1, wn = wave & 1;

  f32x16 a00, a01, a10, a11;
#pragma unroll
  for (int r = 0; r < 16; ++r) { a00[r] = 0.f; a01[r] = 0.f; a10[r] = 0.f; a11[r] = 0.f; }

#pragma unroll
  for (int ks = 0; ks < 8; ++ks) {
    int r0 = wm * 64 + lq, r1 = wm * 64 + 32 + lq;
    int c0 = wn * 64 + lq, c1 = wn * 64 + 32 + lq;
    int sl = ks * 2 + h;
    f16x8 af0 = __builtin_bit_cast(f16x8, *(const u32x4*)(&As[r0 * 128 + (sl ^ (r0 & 15)) * 8]));
    f16x8 af1 = __builtin_bit_cast(f16x8, *(const u32x4*)(&As[r1 * 128 + (sl ^ (r1 & 15)) * 8]));
    f16x8 bf0 = __builtin_bit_cast(f16x8, *(const u32x4*)(&Bs[c0 * 128 + (sl ^ (c0 & 15)) * 8]));
    f16x8 bf1 = __builtin_bit_cast(f16x8, *(const u32x4*)(&Bs[c1 * 128 + (sl ^ (c1 & 15)) * 8]));
    a00 = __builtin_amdgcn_mfma_f32_32x32x16_f16(af0, bf0, a00, 0, 0, 0);
    a01 = __builtin_amdgcn_mfma_f32_32x32x16_f16(af0, bf1, a01, 0, 0, 0);
    a10 = __builtin_amdgcn_mfma_f32_32x32x16_f16(af1, bf0, a10, 0, 0, 0);
    a11 = __builtin_amdgcn_mfma_f32_32x32x16_f16(af1, bf1, a11, 0, 0, 0);
  }

  // q scale folds log2e for the exp2-space softmax in k_attn
  const float scale = (float)(0.17677669529663687 * 1.4426950408889634);
  float bias0 = qkvb[nc * 128 + wn * 64 + lq];
  float bias1 = qkvb[nc * 128 + wn * 64 + 32 + lq];

#define EPI_QK(ACC, MI, NI, DST, DO_SCALE)                                    \
  {                                                                           \
    int head = wn * 2 + (NI);                                                 \
    size_t whb = (size_t)(win * 4 + head);                                    \
    float bc = (NI) ? bias1 : bias0;                                          \
    _Pragma("unroll")                                                         \
    for (int r = 0; r < 16; ++r) {                                            \
      int row32 = (r & 3) + 8 * (r >> 2) + 4 * h;                             \
      int n = t128 * 128 + wm * 64 + (MI) * 32 + row32;                       \
      float val = ACC[r] + bc;                                                \
      if (DO_SCALE) val *= scale;                                             \
      DST[(whb * 512 + n) * 32 + lq] = __float2bfloat16(val);                 \
    }                                                                         \
  }
#define EPI_V(ACC, MI, NI)                                                    \
  {                                                                           \
    int head = wn * 2 + (NI);                                                 \
    size_t whb = (size_t)(win * 4 + head);                                    \
    float bc = (NI) ? bias1 : bias0;                                          \
    _Pragma("unroll")                                                         \
    for (int g = 0; g < 4; ++g) {                                             \
      int n0 = t128 * 128 + wm * 64 + (MI) * 32 + g * 8 + 4 * h;              \
      uint2 u = make_uint2(pkbf16(ACC[g * 4 + 0] + bc, ACC[g * 4 + 1] + bc),  \
                           pkbf16(ACC[g * 4 + 2] + bc, ACC[g * 4 + 3] + bc)); \
      *(uint2*)(vb + (whb * 32 + lq) * 512 + n0) = u;                         \
    }                                                                         \
  }

  if (nc == 0) {
    EPI_QK(a00, 0, 0, qb, 1); EPI_QK(a01, 0, 1, qb, 1);
    EPI_QK(a10, 1, 0, qb, 1); EPI_QK(a11, 1, 1, qb, 1);
  } else if (nc == 1) {
    EPI_QK(a00, 0, 0, kb, 0); EPI_QK(a01, 0, 1, kb, 0);
    EPI_QK(a10, 1, 0, kb, 0); EPI_QK(a11, 1, 1, kb, 0);
  } else {
    EPI_V(a00, 0, 0); EPI_V(a01, 0, 1);
    EPI_V(a10, 1, 0); EPI_V(a11, 1, 1);
  }
}

// ------- attention: dual-stream, fixed-max exp2 softmax (no running max) ---
// grid 512 = 64 win * 4 head * 2 half; block 256 (4 waves). Each wave owns
// queries [half*256 + wave*64, +64): stream A = first 32, stream B = next 32.
// p = exp2(s) raw: shift-invariant softmax, |s| bounded (~15); masked keys
// s-144 -> exp2 -> exactly 0. l accumulates lane-locally; one shfl at end.
__global__ __launch_bounds__(256) void k_attn(
    const __hip_bfloat16* __restrict__ qb, const __hip_bfloat16* __restrict__ kb,
    const __hip_bfloat16* __restrict__ vb, const unsigned short* __restrict__ biasb,
    _Float16* __restrict__ ao) {
  __shared__ unsigned short Ks[2][64 * 40];   // keys x 32ch, 80B rows
  __shared__ unsigned short Vs[2][32 * 72];   // d x 64 keys, 144B rows
  __shared__ unsigned char regid[512];

  const int tid = threadIdx.x;
  const int b = blockIdx.x;
  const int win = b >> 3, head = (b >> 1) & 3, half = b & 1;
  const int wh = win >> 4, ww = (win >> 2) & 3, wd = win & 3;
  const int wave = tid >> 6, lane = tid & 63;
  const int lq = lane & 31, h = lane >> 5;
  const int qA = half * 256 + wave * 64 + lq;
  const int qB = qA + 32;
  const bool has_mask = (wh == 3) || (ww == 3) || (wd == 3);

  unsigned rnA = 0, rnB = 0;
  if (has_mask) {
#pragma unroll
    for (int i = 0; i < 2; ++i) {
      int n = tid + i * 256;
      int lh = n >> 6, lw = (n >> 3) & 7, ld = n & 7;
      regid[n] = (unsigned char)(((wh == 3) ? (lh < 4 ? 1 : 2) : 0) * 9 +
                                 ((ww == 3) ? (lw < 4 ? 1 : 2) : 0) * 3 +
                                 ((wd == 3) ? (ld < 4 ? 1 : 2) : 0));
    }
    {
      int n = qA;
      int lh = n >> 6, lw = (n >> 3) & 7, ld = n & 7;
      rnA = (unsigned)(((wh == 3) ? (lh < 4 ? 1 : 2) : 0) * 9 +
                       ((ww == 3) ? (lw < 4 ? 1 : 2) : 0) * 3 +
                       ((wd == 3) ? (ld < 4 ? 1 : 2) : 0));
      n = qB; lh = n >> 6; lw = (n >> 3) & 7; ld = n & 7;
      rnB = (unsigned)(((wh == 3) ? (lh < 4 ? 1 : 2) : 0) * 9 +
                       ((ww == 3) ? (lw < 4 ? 1 : 2) : 0) * 3 +
                       ((wd == 3) ? (ld < 4 ? 1 : 2) : 0));
    }
  }

  const size_t whb = (size_t)(win * 4 + head);
  const __hip_bfloat16* qrowA = qb + (whb * 512 + qA) * 32;
  const __hip_bfloat16* qrowB = qb + (whb * 512 + qB) * 32;
  bf16x8 qfA0 = __builtin_bit_cast(bf16x8, *(const u32x4*)(qrowA + h * 8));
  bf16x8 qfA1 = __builtin_bit_cast(bf16x8, *(const u32x4*)(qrowA + 16 + h * 8));
  bf16x8 qfB0 = __builtin_bit_cast(bf16x8, *(const u32x4*)(qrowB + h * 8));
  bf16x8 qfB1 = __builtin_bit_cast(bf16x8, *(const u32x4*)(qrowB + 16 + h * 8));

  const __hip_bfloat16* kg = kb + whb * 512 * 32;
  const __hip_bfloat16* vg = vb + whb * 32 * 512;
  const unsigned short* browA = biasb + ((size_t)head * 512 + qA) * 512;
  const unsigned short* browB = biasb + ((size_t)head * 512 + qB) * 512;

  float lA = 0.f, lB = 0.f;
  f32x16 oA, oB;
#pragma unroll
  for (int r = 0; r < 16; ++r) { oA[r] = 0.f; oB[r] = 0.f; }

  // async staging: global->reg early, reg->LDS late (T14)
  const int srow = tid >> 2, sseg = tid & 3;
  const int svd = tid >> 3, sseg2 = tid & 7;
  u32x4 kreg, vreg;
#define GLOAD(CHK)                                                            \
  { kreg = *(const u32x4*)(kg + ((CHK) * 64 + srow) * 32 + sseg * 8);         \
    vreg = *(const u32x4*)(vg + svd * 512 + (CHK) * 64 + sseg2 * 8); }
#define LWRITE(BUF)                                                           \
  { *(u32x4*)(&Ks[BUF][srow * 40 + sseg * 8]) = kreg;                         \
    *(u32x4*)(&Vs[BUF][svd * 72 + sseg2 * 8]) = vreg; }

  GLOAD(0); LWRITE(0);
  __syncthreads();

  // one stream (32 queries) over a 32-key subtile; bias preloaded in bb[4]
  auto stream_step = [&](f32x16 c, const uint2* bb, unsigned rn,
                         float& l_run, f32x16& o,
                         bf16x8 vf0, bf16x8 vf1, int kbase) {
    float p[16];
#pragma unroll
    for (int j = 0; j < 4; ++j) {
      float b0 = __uint_as_float(bb[j].x << 16);
      float b1 = __uint_as_float(bb[j].x & 0xFFFF0000u);
      float b2 = __uint_as_float(bb[j].y << 16);
      float b3 = __uint_as_float(bb[j].y & 0xFFFF0000u);
      if (has_mask) {
        unsigned rm = *(const unsigned*)(&regid[kbase + h * 4 + j * 8]);
        b0 += ((rm & 255u) == rn) ? 0.f : -144.2695041f;
        b1 += (((rm >> 8) & 255u) == rn) ? 0.f : -144.2695041f;
        b2 += (((rm >> 16) & 255u) == rn) ? 0.f : -144.2695041f;
        b3 += (((rm >> 24)) == rn) ? 0.f : -144.2695041f;
      }
      p[j * 4 + 0] = exp2f(c[j * 4 + 0] + b0);
      p[j * 4 + 1] = exp2f(c[j * 4 + 1] + b1);
      p[j * 4 + 2] = exp2f(c[j * 4 + 2] + b2);
      p[j * 4 + 3] = exp2f(c[j * 4 + 3] + b3);
    }
    float s0 = (p[0] + p[1]) + (p[2] + p[3]);
    float s1 = (p[4] + p[5]) + (p[6] + p[7]);
    float s2 = (p[8] + p[9]) + (p[10] + p[11]);
    float s3 = (p[12] + p[13]) + (p[14] + p[15]);
    l_run += (s0 + s1) + (s2 + s3);
    unsigned bw[8];
#pragma unroll
    for (int g = 0; g < 8; ++g) bw[g] = pkbf16(p[2 * g], p[2 * g + 1]);
#pragma unroll
    for (int kc = 0; kc < 2; ++kc) {
      unsigned b0 = bw[kc * 4 + 0], b1 = bw[kc * 4 + 1];
      unsigned b2 = bw[kc * 4 + 2], b3 = bw[kc * 4 + 3];
      unsigned sb0 = __shfl_xor(b0, 32, 64), sb1 = __shfl_xor(b1, 32, 64);
      unsigned sb2 = __shfl_xor(b2, 32, 64), sb3 = __shfl_xor(b3, 32, 64);
      u32x4 pw;
      pw.x = h ? sb2 : b0;
      pw.y = h ? sb3 : b1;
      pw.z = h ? b2 : sb0;
      pw.w = h ? b3 : sb1;
      bf16x8 pf = __builtin_bit_cast(bf16x8, pw);
      o = __builtin_amdgcn_mfma_f32_32x32x16_bf16(kc ? vf1 : vf0, pf, o, 0, 0, 0);
    }
  };

  for (int chk = 0; chk < 8; ++chk) {
    const int cur = chk & 1;
    if (chk < 7) GLOAD(chk + 1);           // issue next-tile loads (hide under compute)

#pragma unroll
    for (int sub = 0; sub < 2; ++sub) {
      const int kbase = chk * 64 + sub * 32;
      // bias prefetch BEFORE the QK MFMAs (hide L2 latency under MFMA+LDS)
      uint2 bbA[4], bbB[4];
#pragma unroll
      for (int j = 0; j < 4; ++j) {
        bbA[j] = *(const uint2*)(browA + kbase + h * 4 + j * 8);
        bbB[j] = *(const uint2*)(browB + kbase + h * 4 + j * 8);
      }
      const unsigned short* KsC = Ks[cur];
      const unsigned short* VsC = Vs[cur];
      bf16x8 kf0 = __builtin_bit_cast(bf16x8, *(const u32x4*)(&KsC[(sub * 32 + lq) * 40 + h * 8]));
      bf16x8 kf1 = __builtin_bit_cast(bf16x8, *(const u32x4*)(&KsC[(sub * 32 + lq) * 40 + 16 + h * 8]));
      f32x16 cA, cB;
#pragma unroll
      for (int r = 0; r < 16; ++r) { cA[r] = 0.f; cB[r] = 0.f; }
      cA = __builtin_amdgcn_mfma_f32_32x32x16_bf16(kf0, qfA0, cA, 0, 0, 0);
      cA = __builtin_amdgcn_mfma_f32_32x32x16_bf16(kf1, qfA1, cA, 0, 0, 0);
      cB = __builtin_amdgcn_mfma_f32_32x32x16_bf16(kf0, qfB0, cB, 0, 0, 0);
      cB = __builtin_amdgcn_mfma_f32_32x32x16_bf16(kf1, qfB1, cB, 0, 0, 0);
      bf16x8 vf0 = __builtin_bit_cast(bf16x8, *(const u32x4*)(&VsC[lq * 72 + sub * 32 + h * 8]));
      bf16x8 vf1 = __builtin_bit_cast(bf16x8, *(const u32x4*)(&VsC[lq * 72 + sub * 32 + 16 + h * 8]));
      stream_step(cA, bbA, rnA, lA, oA, vf0, vf1, kbase);
      stream_step(cB, bbB, rnB, lB, oB, vf0, vf1, kbase);
    }

    if (chk < 7) LWRITE(cur ^ 1);          // reg->LDS after compute (prev readers barrier-separated)
    __syncthreads();
  }

  // lane-local l covers 16 of each 32-key subtile; lane^32 holds the rest
  lA += __shfl_xor(lA, 32, 64);
  lB += __shfl_xor(lB, 32, 64);

  const float invA = 1.f / lA, invB = 1.f / lB;
  _Float16* orowA = ao + ((size_t)(win * 512 + qA)) * 128 + head * 32;
  _Float16* orowB = ao + ((size_t)(win * 512 + qB)) * 128 + head * 32;
#pragma unroll
  for (int j = 0; j < 4; ++j) {
    int d0 = j * 8 + h * 4;
    f16x4 tA, tB;
    tA[0] = (_Float16)(oA[j * 4 + 0] * invA); tA[1] = (_Float16)(oA[j * 4 + 1] * invA);
    tA[2] = (_Float16)(oA[j * 4 + 2] * invA); tA[3] = (_Float16)(oA[j * 4 + 3] * invA);
    tB[0] = (_Float16)(oB[j * 4 + 0] * invB); tB[1] = (_Float16)(oB[j * 4 + 1] * invB);
    tB[2] = (_Float16)(oB[j * 4 + 2] * invB); tB[3] = (_Float16)(oB[j * 4 + 3] * invB);
    *(f16x4*)(orowA + d0) = tA;
    *(f16x4*)(orowB + d0) = tB;
  }
}

// ------- proj GEMM (fp16 MFMA) + reverse partition + reverse roll ----------
__global__ __launch_bounds__(256, 2) void k_proj(
    const _Float16* __restrict__ ao, const _Float16* __restrict__ wp,
    const float* __restrict__ pb, float* __restrict__ out) {
  __shared__ unsigned short As[128 * 128];
  __shared__ unsigned short Bs[128 * 128];
  const int tid = threadIdx.x;
  const int mt = blockIdx.x;
  const int win = mt >> 2, t128 = mt & 3;
  const int wh = win >> 4, ww = (win >> 2) & 3, wd = win & 3;

#pragma unroll
  for (int u = 0; u < 8; ++u) {
    int f = u * 256 + tid;
    int row = f >> 4, seg = f & 15;
    u32x4 av = *(const u32x4*)(ao + ((size_t)(win * 512 + t128 * 128 + row)) * 128 + seg * 8);
    int slot = seg ^ (row & 15);
    *(u32x4*)(&As[row * 128 + slot * 8]) = av;
  }
#pragma unroll
  for (int u = 0; u < 8; ++u) {
    int f = u * 256 + tid;
    int row = f >> 4, seg = f & 15;
    u32x4 wv = *(const u32x4*)(wp + row * 128 + seg * 8);
    int slot = seg ^ (row & 15);
    *(u32x4*)(&Bs[row * 128 + slot * 8]) = wv;
  }
  __syncthreads();

  const int wave = tid >> 6, lane = tid & 63;
  const int lq = lane & 31, h = lane >> 5;
  const int wm = wave >> 1, wn = wave & 1;

  f32x16 a00, a01, a10, a11;
#pragma unroll
  for (int r = 0; r < 16; ++r) { a00[r] = 0.f; a01[r] = 0.f; a10[r] = 0.f; a11[r] = 0.f; }

#pragma unroll
  for (int ks = 0; ks < 8; ++ks) {
    int r0 = wm * 64 + lq, r1 = wm * 64 + 32 + lq;
    int c0 = wn * 64 + lq, c1 = wn * 64 + 32 + lq;
    int sl = ks * 2 + h;
    f16x8 af0 = __builtin_bit_cast(f16x8, *(const u32x4*)(&As[r0 * 128 + (sl ^ (r0 & 15)) * 8]));
    f16x8 af1 = __builtin_bit_cast(f16x8, *(const u32x4*)(&As[r1 * 128 + (sl ^ (r1 & 15)) * 8]));
    f16x8 bf0 = __builtin_bit_cast(f16x8, *(const u32x4*)(&Bs[c0 * 128 + (sl ^ (c0 & 15)) * 8]));
    f16x8 bf1 = __builtin_bit_cast(f16x8, *(const u32x4*)(&Bs[c1 * 128 + (sl ^ (c1 & 15)) * 8]));
    a00 = __builtin_amdgcn_mfma_f32_32x32x16_f16(af0, bf0, a00, 0, 0, 0);
    a01 = __builtin_amdgcn_mfma_f32_32x32x16_f16(af0, bf1, a01, 0, 0, 0);
    a10 = __builtin_amdgcn_mfma_f32_32x32x16_f16(af1, bf0, a10, 0, 0, 0);
    a11 = __builtin_amdgcn_mfma_f32_32x32x16_f16(af1, bf1, a11, 0, 0, 0);
  }

  float bias0 = pb[wn * 64 + lq];
  float bias1 = pb[wn * 64 + 32 + lq];

#define EPI_P(ACC, MI, NI)                                                    \
  {                                                                           \
    int col = wn * 64 + (NI) * 32 + lq;                                       \
    float bc = (NI) ? bias1 : bias0;                                          \
    _Pragma("unroll")                                                         \
    for (int r = 0; r < 16; ++r) {                                            \
      int row32 = (r & 3) + 8 * (r >> 2) + 4 * h;                             \
      int n = t128 * 128 + wm * 64 + (MI) * 32 + row32;                       \
      int lh = n >> 6, lw = (n >> 3) & 7, ld = n & 7;                         \
      int dh = (wh * 8 + lh + 4) & 31;                                        \
      int dw = (ww * 8 + lw + 4) & 31;                                        \
      int dd = (wd * 8 + ld + 4) & 31;                                        \
      out[(size_t)((dh * 32 + dw) * 32 + dd) * 128 + col] = ACC[r] + bc;      \
    }                                                                         \
  }
  EPI_P(a00, 0, 0); EPI_P(a01, 0, 1); EPI_P(a10, 1, 0); EPI_P(a11, 1, 1);
}

extern "C" void kernel_launch(void* const* d_in, const int* in_sizes, int n_in,
                              void* d_out, int out_size, void* d_ws, size_t ws_size,
                              hipStream_t stream) {
  const float* x    = (const float*)d_in[0];
  const float* qkvw = (const float*)d_in[1];
  const float* qkvb = (const float*)d_in[2];
  const float* pw   = (const float*)d_in[3];
  const float* pb   = (const float*)d_in[4];
  const float* rpb  = (const float*)d_in[5];
  const int*   rpi  = (const int*)d_in[6];
  float* out = (float*)d_out;

  char* base = (char*)d_ws;
  __hip_bfloat16* qbuf = (__hip_bfloat16*)(base);
  __hip_bfloat16* kbuf = (__hip_bfloat16*)(base + 8388608);
  __hip_bfloat16* vbuf = (__hip_bfloat16*)(base + 16777216);
  _Float16* ao = (_Float16*)(base + 25165824);
  unsigned short* biasb = (unsigned short*)(base + 33554432);
  _Float16* wq = (_Float16*)(base + 35651584);
  _Float16* wp = (_Float16*)(base + 35749888);

  hipLaunchKernelGGL(k_bias, dim3(1024), dim3(256), 0, stream, rpb, rpi, biasb, qkvw, pw, wq, wp);
  hipLaunchKernelGGL(k_qkv,  dim3(768),  dim3(256), 0, stream, x, wq, qkvb, qbuf, kbuf, vbuf);
  hipLaunchKernelGGL(k_attn, dim3(512),  dim3(256), 0, stream, qbuf, kbuf, vbuf, biasb, ao);
  hipLaunchKernelGGL(k_proj, dim3(256),  dim3(256), 0, stream, ao, wp, pb, out);
}

// Round 13
// 144.402 us; speedup vs baseline: 1.0974x; 1.0775x over previous
//
#include <hip/hip_runtime.h>
#include <hip/hip_bf16.h>
#include <math.h>

// ShiftedWindowAttention 3D (Swin): 32^3, C=128, heads=4, hd=32, window 8^3
// (N=512), shift 4^3, 64 windows.
// Round 10 kernel, third submission (R11/R12 benches were GPU-acquisition
// timeouts): occupancy fix. R10 post-mortem: dual-stream grid 512 = 2
// waves/SIMD was the binding constraint (latency-bound; cutting VALU made it
// slower, VALUBusy 46->38% while dur rose). Back to grid 1024 (win, head,
// q-quarter), 32q/wave single-stream = 4 waves/SIMD, VGPR ~90 w/
// __launch_bounds__(256,4). KEEP fixed-max exp2 softmax + bf16 bias +
// mask-skip + K/V dbuf. Bias loads issued BEFORE next-chunk GLOAD so the
// prefetch isn't drained by the bias vmcnt wait.
// k_qkv/k_proj/k_bias unchanged.
//
// ws layout (bytes):
//   qb  bf16 [256][512][32]  @ 0          (8,388,608)   q pre-scaled by hd^-.5*log2e
//   kb  bf16 [256][512][32]  @ 8388608
//   vb  bf16 [256][32][512]  @ 16777216   (V transposed per win-head)
//   ao  f16  [64*512][128]   @ 25165824   (8,388,608)
//   biasb bf16 [4][512][512] @ 33554432   (2,097,152)   pre-scaled by log2e
//   wq  f16  [384][128]      @ 35651584   (98,304)
//   wp  f16  [128][128]      @ 35749888   (32,768)

#define NTOT 262144

typedef float     f32x16 __attribute__((ext_vector_type(16)));
typedef __bf16    bf16x8 __attribute__((ext_vector_type(8)));
typedef _Float16  f16x8  __attribute__((ext_vector_type(8)));
typedef _Float16  f16x4  __attribute__((ext_vector_type(4)));
typedef unsigned int u32x4 __attribute__((ext_vector_type(4)));

__device__ __forceinline__ unsigned int pkbf16(float a, float b) {
  __hip_bfloat16 x = __float2bfloat16(a), y = __float2bfloat16(b);
  return (unsigned int)__builtin_bit_cast(unsigned short, x) |
         ((unsigned int)__builtin_bit_cast(unsigned short, y) << 16);
}
__device__ __forceinline__ unsigned short bfbits(float v) {
  return __builtin_bit_cast(unsigned short, __float2bfloat16(v));
}

// ------- bias precompute (bf16, log2e-scaled) + weight fp16 conversion -----
__global__ void k_bias(const float* __restrict__ rpb, const int* __restrict__ rpi,
                       unsigned short* __restrict__ biasb,
                       const float* __restrict__ qkvw, const float* __restrict__ projw,
                       _Float16* __restrict__ wq, _Float16* __restrict__ wp) {
  int idx = blockIdx.x * 256 + threadIdx.x;
  int t = rpi[idx];
  float4 b4 = *reinterpret_cast<const float4*>(rpb + 4 * t);
  const float L2E = 1.4426950408889634f;
  biasb[0 * NTOT + idx] = bfbits(b4.x * L2E);
  biasb[1 * NTOT + idx] = bfbits(b4.y * L2E);
  biasb[2 * NTOT + idx] = bfbits(b4.z * L2E);
  biasb[3 * NTOT + idx] = bfbits(b4.w * L2E);
  if (idx < 65536) {
    if (idx < 49152) wq[idx] = (_Float16)qkvw[idx];
    else             wp[idx - 49152] = (_Float16)projw[idx - 49152];
  }
}

// ------- fused roll + partition + QKV GEMM on fp16 MFMA --------------------
__global__ __launch_bounds__(256, 2) void k_qkv(
    const float* __restrict__ x, const _Float16* __restrict__ wq,
    const float* __restrict__ qkvb,
    __hip_bfloat16* __restrict__ qb, __hip_bfloat16* __restrict__ kb,
    __hip_bfloat16* __restrict__ vb) {
  __shared__ unsigned short As[128 * 128];
  __shared__ unsigned short Bs[128 * 128];
  const int tid = threadIdx.x;
  const int bm = blockIdx.x;
  const int nc = bm >> 8;              // 0=q 1=k 2=v
  const int mt = bm & 255;
  const int win = mt >> 2, t128 = mt & 3;
  const int wh = win >> 4, ww = (win >> 2) & 3, wd = win & 3;

#pragma unroll
  for (int u = 0; u < 8; ++u) {
    int f = u * 256 + tid;
    int row = f >> 4, seg = f & 15;
    int n = t128 * 128 + row;
    int lh = n >> 6, lw = (n >> 3) & 7, ld = n & 7;
    int sh = (wh * 8 + lh + 4) & 31;
    int sw = (ww * 8 + lw + 4) & 31;
    int sd = (wd * 8 + ld + 4) & 31;
    const float* src = x + ((sh * 32 + sw) * 32 + sd) * 128 + seg * 8;
    float4 a0 = *(const float4*)src;
    float4 a1 = *(const float4*)(src + 4);
    f16x8 hv;
    hv[0] = (_Float16)a0.x; hv[1] = (_Float16)a0.y;
    hv[2] = (_Float16)a0.z; hv[3] = (_Float16)a0.w;
    hv[4] = (_Float16)a1.x; hv[5] = (_Float16)a1.y;
    hv[6] = (_Float16)a1.z; hv[7] = (_Float16)a1.w;
    int slot = seg ^ (row & 15);
    *(u32x4*)(&As[row * 128 + slot * 8]) = __builtin_bit_cast(u32x4, hv);
  }
#pragma unroll
  for (int u = 0; u < 8; ++u) {
    int f = u * 256 + tid;
    int row = f >> 4, seg = f & 15;
    u32x4 wv = *(const u32x4*)(wq + (nc * 128 + row) * 128 + seg * 8);
    int slot = seg ^ (row & 15);
    *(u32x4*)(&Bs[row * 128 + slot * 8]) = wv;
  }
  __syncthreads();

  const int wave = tid >> 6, lane = tid & 63;
  const int lq = lane & 31, h = lane >> 5;
  const int wm = wave >> 1, wn = wave & 1;

  f32x16 a00, a01, a10, a11;
#pragma unroll
  for (int r = 0; r < 16; ++r) { a00[r] = 0.f; a01[r] = 0.f; a10[r] = 0.f; a11[r] = 0.f; }

#pragma unroll
  for (int ks = 0; ks < 8; ++ks) {
    int r0 = wm * 64 + lq, r1 = wm * 64 + 32 + lq;
    int c0 = wn * 64 + lq, c1 = wn * 64 + 32 + lq;
    int sl = ks * 2 + h;
    f16x8 af0 = __builtin_bit_cast(f16x8, *(const u32x4*)(&As[r0 * 128 + (sl ^ (r0 & 15)) * 8]));
    f16x8 af1 = __builtin_bit_cast(f16x8, *(const u32x4*)(&As[r1 * 128 + (sl ^ (r1 & 15)) * 8]));
    f16x8 bf0 = __builtin_bit_cast(f16x8, *(const u32x4*)(&Bs[c0 * 128 + (sl ^ (c0 & 15)) * 8]));
    f16x8 bf1 = __builtin_bit_cast(f16x8, *(const u32x4*)(&Bs[c1 * 128 + (sl ^ (c1 & 15)) * 8]));
    a00 = __builtin_amdgcn_mfma_f32_32x32x16_f16(af0, bf0, a00, 0, 0, 0);
    a01 = __builtin_amdgcn_mfma_f32_32x32x16_f16(af0, bf1, a01, 0, 0, 0);
    a10 = __builtin_amdgcn_mfma_f32_32x32x16_f16(af1, bf0, a10, 0, 0, 0);
    a11 = __builtin_amdgcn_mfma_f32_32x32x16_f16(af1, bf1, a11, 0, 0, 0);
  }

  // q scale folds log2e for the exp2-space softmax in k_attn
  const float scale = (float)(0.17677669529663687 * 1.4426950408889634);
  float bias0 = qkvb[nc * 128 + wn * 64 + lq];
  float bias1 = qkvb[nc * 128 + wn * 64 + 32 + lq];

#define EPI_QK(ACC, MI, NI, DST, DO_SCALE)                                    \
  {                                                                           \
    int head = wn * 2 + (NI);                                                 \
    size_t whb = (size_t)(win * 4 + head);                                    \
    float bc = (NI) ? bias1 : bias0;                                          \
    _Pragma("unroll")                                                         \
    for (int r = 0; r < 16; ++r) {                                            \
      int row32 = (r & 3) + 8 * (r >> 2) + 4 * h;                             \
      int n = t128 * 128 + wm * 64 + (MI) * 32 + row32;                       \
      float val = ACC[r] + bc;                                                \
      if (DO_SCALE) val *= scale;                                             \
      DST[(whb * 512 + n) * 32 + lq] = __float2bfloat16(val);                 \
    }                                                                         \
  }
#define EPI_V(ACC, MI, NI)                                                    \
  {                                                                           \
    int head = wn * 2 + (NI);                                                 \
    size_t whb = (size_t)(win * 4 + head);                                    \
    float bc = (NI) ? bias1 : bias0;                                          \
    _Pragma("unroll")                                                         \
    for (int g = 0; g < 4; ++g) {                                             \
      int n0 = t128 * 128 + wm * 64 + (MI) * 32 + g * 8 + 4 * h;              \
      uint2 u = make_uint2(pkbf16(ACC[g * 4 + 0] + bc, ACC[g * 4 + 1] + bc),  \
                           pkbf16(ACC[g * 4 + 2] + bc, ACC[g * 4 + 3] + bc)); \
      *(uint2*)(vb + (whb * 32 + lq) * 512 + n0) = u;                         \
    }                                                                         \
  }

  if (nc == 0) {
    EPI_QK(a00, 0, 0, qb, 1); EPI_QK(a01, 0, 1, qb, 1);
    EPI_QK(a10, 1, 0, qb, 1); EPI_QK(a11, 1, 1, qb, 1);
  } else if (nc == 1) {
    EPI_QK(a00, 0, 0, kb, 0); EPI_QK(a01, 0, 1, kb, 0);
    EPI_QK(a10, 1, 0, kb, 0); EPI_QK(a11, 1, 1, kb, 0);
  } else {
    EPI_V(a00, 0, 0); EPI_V(a01, 0, 1);
    EPI_V(a10, 1, 0); EPI_V(a11, 1, 1);
  }
}

// ------- attention: 32q/wave, 4 blocks/CU, fixed-max exp2 softmax ----------
// grid 1024 = 64 win * 4 head * 4 qblk; block 256 (4 waves, each 32 queries).
// p = exp2(s) raw (shift-invariant; masked s-144 -> 0). Bias for the chunk
// loaded BEFORE the next-chunk K/V prefetch so its vmcnt wait doesn't drain
// the prefetch.
__global__ __launch_bounds__(256, 4) void k_attn(
    const __hip_bfloat16* __restrict__ qb, const __hip_bfloat16* __restrict__ kb,
    const __hip_bfloat16* __restrict__ vb, const unsigned short* __restrict__ biasb,
    _Float16* __restrict__ ao) {
  __shared__ unsigned short Ks[2][64 * 40];   // keys x 32ch, 80B rows
  __shared__ unsigned short Vs[2][32 * 72];   // d x 64 keys, 144B rows
  __shared__ unsigned char regid[512];

  const int tid = threadIdx.x;
  const int b = blockIdx.x;
  const int win = b >> 4, head = (b >> 2) & 3, qblk = b & 3;
  const int wh = win >> 4, ww = (win >> 2) & 3, wd = win & 3;
  const int wave = tid >> 6, lane = tid & 63;
  const int lq = lane & 31, h = lane >> 5;
  const int q = qblk * 128 + wave * 32 + lq;
  const bool has_mask = (wh == 3) || (ww == 3) || (wd == 3);

  unsigned rn = 0;
  if (has_mask) {
#pragma unroll
    for (int i = 0; i < 2; ++i) {
      int n = tid + i * 256;
      int lh = n >> 6, lw = (n >> 3) & 7, ld = n & 7;
      regid[n] = (unsigned char)(((wh == 3) ? (lh < 4 ? 1 : 2) : 0) * 9 +
                                 ((ww == 3) ? (lw < 4 ? 1 : 2) : 0) * 3 +
                                 ((wd == 3) ? (ld < 4 ? 1 : 2) : 0));
    }
    int lh = q >> 6, lw = (q >> 3) & 7, ld = q & 7;
    rn = (unsigned)(((wh == 3) ? (lh < 4 ? 1 : 2) : 0) * 9 +
                    ((ww == 3) ? (lw < 4 ? 1 : 2) : 0) * 3 +
                    ((wd == 3) ? (ld < 4 ? 1 : 2) : 0));
  }

  const size_t whb = (size_t)(win * 4 + head);
  const __hip_bfloat16* qrow = qb + (whb * 512 + q) * 32;
  bf16x8 qf0 = __builtin_bit_cast(bf16x8, *(const u32x4*)(qrow + h * 8));
  bf16x8 qf1 = __builtin_bit_cast(bf16x8, *(const u32x4*)(qrow + 16 + h * 8));

  const __hip_bfloat16* kg = kb + whb * 512 * 32;
  const __hip_bfloat16* vg = vb + whb * 32 * 512;
  const unsigned short* brow = biasb + ((size_t)head * 512 + q) * 512;

  float l_run = 0.f;
  f32x16 o;
#pragma unroll
  for (int r = 0; r < 16; ++r) o[r] = 0.f;

  // async staging: global->reg early, reg->LDS late (T14)
  const int srow = tid >> 2, sseg = tid & 3;
  const int svd = tid >> 3, sseg2 = tid & 7;
  u32x4 kreg, vreg;
#define GLOAD(CHK)                                                            \
  { kreg = *(const u32x4*)(kg + ((CHK) * 64 + srow) * 32 + sseg * 8);         \
    vreg = *(const u32x4*)(vg + svd * 512 + (CHK) * 64 + sseg2 * 8); }
#define LWRITE(BUF)                                                           \
  { *(u32x4*)(&Ks[BUF][srow * 40 + sseg * 8]) = kreg;                         \
    *(u32x4*)(&Vs[BUF][svd * 72 + sseg2 * 8]) = vreg; }

  GLOAD(0); LWRITE(0);
  __syncthreads();

  for (int chk = 0; chk < 8; ++chk) {
    const int cur = chk & 1;

    // bias for BOTH subs of this chunk, issued before the K/V prefetch:
    // consuming bb then waits only on these loads, prefetch stays in flight.
    uint2 bb[2][4];
#pragma unroll
    for (int sub = 0; sub < 2; ++sub)
#pragma unroll
      for (int j = 0; j < 4; ++j)
        bb[sub][j] = *(const uint2*)(brow + chk * 64 + sub * 32 + h * 4 + j * 8);

    if (chk < 7) GLOAD(chk + 1);           // next-tile loads (hide under compute)

#pragma unroll
    for (int sub = 0; sub < 2; ++sub) {
      const int kbase = chk * 64 + sub * 32;
      const unsigned short* KsC = Ks[cur];
      const unsigned short* VsC = Vs[cur];
      bf16x8 kf0 = __builtin_bit_cast(bf16x8, *(const u32x4*)(&KsC[(sub * 32 + lq) * 40 + h * 8]));
      bf16x8 kf1 = __builtin_bit_cast(bf16x8, *(const u32x4*)(&KsC[(sub * 32 + lq) * 40 + 16 + h * 8]));
      f32x16 c;
#pragma unroll
      for (int r = 0; r < 16; ++r) c[r] = 0.f;
      c = __builtin_amdgcn_mfma_f32_32x32x16_bf16(kf0, qf0, c, 0, 0, 0);
      c = __builtin_amdgcn_mfma_f32_32x32x16_bf16(kf1, qf1, c, 0, 0, 0);

      float p[16];
#pragma unroll
      for (int j = 0; j < 4; ++j) {
        float b0 = __uint_as_float(bb[sub][j].x << 16);
        float b1 = __uint_as_float(bb[sub][j].x & 0xFFFF0000u);
        float b2 = __uint_as_float(bb[sub][j].y << 16);
        float b3 = __uint_as_float(bb[sub][j].y & 0xFFFF0000u);
        if (has_mask) {
          unsigned rm = *(const unsigned*)(&regid[kbase + h * 4 + j * 8]);
          b0 += ((rm & 255u) == rn) ? 0.f : -144.2695041f;
          b1 += (((rm >> 8) & 255u) == rn) ? 0.f : -144.2695041f;
          b2 += (((rm >> 16) & 255u) == rn) ? 0.f : -144.2695041f;
          b3 += (((rm >> 24)) == rn) ? 0.f : -144.2695041f;
        }
        p[j * 4 + 0] = exp2f(c[j * 4 + 0] + b0);
        p[j * 4 + 1] = exp2f(c[j * 4 + 1] + b1);
        p[j * 4 + 2] = exp2f(c[j * 4 + 2] + b2);
        p[j * 4 + 3] = exp2f(c[j * 4 + 3] + b3);
      }
      float s0 = (p[0] + p[1]) + (p[2] + p[3]);
      float s1 = (p[4] + p[5]) + (p[6] + p[7]);
      float s2 = (p[8] + p[9]) + (p[10] + p[11]);
      float s3 = (p[12] + p[13]) + (p[14] + p[15]);
      l_run += (s0 + s1) + (s2 + s3);

      unsigned bw[8];
#pragma unroll
      for (int g = 0; g < 8; ++g) bw[g] = pkbf16(p[2 * g], p[2 * g + 1]);
#pragma unroll
      for (int kc = 0; kc < 2; ++kc) {
        unsigned b0 = bw[kc * 4 + 0], b1 = bw[kc * 4 + 1];
        unsigned b2 = bw[kc * 4 + 2], b3 = bw[kc * 4 + 3];
        unsigned sb0 = __shfl_xor(b0, 32, 64), sb1 = __shfl_xor(b1, 32, 64);
        unsigned sb2 = __shfl_xor(b2, 32, 64), sb3 = __shfl_xor(b3, 32, 64);
        u32x4 pw;
        pw.x = h ? sb2 : b0;
        pw.y = h ? sb3 : b1;
        pw.z = h ? b2 : sb0;
        pw.w = h ? b3 : sb1;
        bf16x8 pf = __builtin_bit_cast(bf16x8, pw);
        bf16x8 vf = __builtin_bit_cast(bf16x8,
            *(const u32x4*)(&VsC[lq * 72 + sub * 32 + kc * 16 + h * 8]));
        o = __builtin_amdgcn_mfma_f32_32x32x16_bf16(vf, pf, o, 0, 0, 0);
      }
    }

    if (chk < 7) LWRITE(cur ^ 1);          // reg->LDS after compute
    __syncthreads();
  }

  // lane-local l covers 16 of each 32-key subtile; lane^32 holds the rest
  l_run += __shfl_xor(l_run, 32, 64);

  const float inv = 1.f / l_run;
  _Float16* orow = ao + ((size_t)(win * 512 + q)) * 128 + head * 32;
#pragma unroll
  for (int j = 0; j < 4; ++j) {
    int d0 = j * 8 + h * 4;
    f16x4 t;
    t[0] = (_Float16)(o[j * 4 + 0] * inv);
    t[1] = (_Float16)(o[j * 4 + 1] * inv);
    t[2] = (_Float16)(o[j * 4 + 2] * inv);
    t[3] = (_Float16)(o[j * 4 + 3] * inv);
    *(f16x4*)(orow + d0) = t;
  }
}

// ------- proj GEMM (fp16 MFMA) + reverse partition + reverse roll ----------
__global__ __launch_bounds__(256, 2) void k_proj(
    const _Float16* __restrict__ ao, const _Float16* __restrict__ wp,
    const float* __restrict__ pb, float* __restrict__ out) {
  __shared__ unsigned short As[128 * 128];
  __shared__ unsigned short Bs[128 * 128];
  const int tid = threadIdx.x;
  const int mt = blockIdx.x;
  const int win = mt >> 2, t128 = mt & 3;
  const int wh = win >> 4, ww = (win >> 2) & 3, wd = win & 3;

#pragma unroll
  for (int u = 0; u < 8; ++u) {
    int f = u * 256 + tid;
    int row = f >> 4, seg = f & 15;
    u32x4 av = *(const u32x4*)(ao + ((size_t)(win * 512 + t128 * 128 + row)) * 128 + seg * 8);
    int slot = seg ^ (row & 15);
    *(u32x4*)(&As[row * 128 + slot * 8]) = av;
  }
#pragma unroll
  for (int u = 0; u < 8; ++u) {
    int f = u * 256 + tid;
    int row = f >> 4, seg = f & 15;
    u32x4 wv = *(const u32x4*)(wp + row * 128 + seg * 8);
    int slot = seg ^ (row & 15);
    *(u32x4*)(&Bs[row * 128 + slot * 8]) = wv;
  }
  __syncthreads();

  const int wave = tid >> 6, lane = tid & 63;
  const int lq = lane & 31, h = lane >> 5;
  const int wm = wave >> 1, wn = wave & 1;

  f32x16 a00, a01, a10, a11;
#pragma unroll
  for (int r = 0; r < 16; ++r) { a00[r] = 0.f; a01[r] = 0.f; a10[r] = 0.f; a11[r] = 0.f; }

#pragma unroll
  for (int ks = 0; ks < 8; ++ks) {
    int r0 = wm * 64 + lq, r1 = wm * 64 + 32 + lq;
    int c0 = wn * 64 + lq, c1 = wn * 64 + 32 + lq;
    int sl = ks * 2 + h;
    f16x8 af0 = __builtin_bit_cast(f16x8, *(const u32x4*)(&As[r0 * 128 + (sl ^ (r0 & 15)) * 8]));
    f16x8 af1 = __builtin_bit_cast(f16x8, *(const u32x4*)(&As[r1 * 128 + (sl ^ (r1 & 15)) * 8]));
    f16x8 bf0 = __builtin_bit_cast(f16x8, *(const u32x4*)(&Bs[c0 * 128 + (sl ^ (c0 & 15)) * 8]));
    f16x8 bf1 = __builtin_bit_cast(f16x8, *(const u32x4*)(&Bs[c1 * 128 + (sl ^ (c1 & 15)) * 8]));
    a00 = __builtin_amdgcn_mfma_f32_32x32x16_f16(af0, bf0, a00, 0, 0, 0);
    a01 = __builtin_amdgcn_mfma_f32_32x32x16_f16(af0, bf1, a01, 0, 0, 0);
    a10 = __builtin_amdgcn_mfma_f32_32x32x16_f16(af1, bf0, a10, 0, 0, 0);
    a11 = __builtin_amdgcn_mfma_f32_32x32x16_f16(af1, bf1, a11, 0, 0, 0);
  }

  float bias0 = pb[wn * 64 + lq];
  float bias1 = pb[wn * 64 + 32 + lq];

#define EPI_P(ACC, MI, NI)                                                    \
  {                                                                           \
    int col = wn * 64 + (NI) * 32 + lq;                                       \
    float bc = (NI) ? bias1 : bias0;                                          \
    _Pragma("unroll")                                                         \
    for (int r = 0; r < 16; ++r) {                                            \
      int row32 = (r & 3) + 8 * (r >> 2) + 4 * h;                             \
      int n = t128 * 128 + wm * 64 + (MI) * 32 + row32;                       \
      int lh = n >> 6, lw = (n >> 3) & 7, ld = n & 7;                         \
      int dh = (wh * 8 + lh + 4) & 31;                                        \
      int dw = (ww * 8 + lw + 4) & 31;                                        \
      int dd = (wd * 8 + ld + 4) & 31;                                        \
      out[(size_t)((dh * 32 + dw) * 32 + dd) * 128 + col] = ACC[r] + bc;      \
    }                                                                         \
  }
  EPI_P(a00, 0, 0); EPI_P(a01, 0, 1); EPI_P(a10, 1, 0); EPI_P(a11, 1, 1);
}

extern "C" void kernel_launch(void* const* d_in, const int* in_sizes, int n_in,
                              void* d_out, int out_size, void* d_ws, size_t ws_size,
                              hipStream_t stream) {
  const float* x    = (const float*)d_in[0];
  const float* qkvw = (const float*)d_in[1];
  const float* qkvb = (const float*)d_in[2];
  const float* pw   = (const float*)d_in[3];
  const float* pb   = (const float*)d_in[4];
  const float* rpb  = (const float*)d_in[5];
  const int*   rpi  = (const int*)d_in[6];
  float* out = (float*)d_out;

  char* base = (char*)d_ws;
  __hip_bfloat16* qbuf = (__hip_bfloat16*)(base);
  __hip_bfloat16* kbuf = (__hip_bfloat16*)(base + 8388608);
  __hip_bfloat16* vbuf = (__hip_bfloat16*)(base + 16777216);
  _Float16* ao = (_Float16*)(base + 25165824);
  unsigned short* biasb = (unsigned short*)(base + 33554432);
  _Float16* wq = (_Float16*)(base + 35651584);
  _Float16* wp = (_Float16*)(base + 35749888);

  hipLaunchKernelGGL(k_bias, dim3(1024), dim3(256), 0, stream, rpb, rpi, biasb, qkvw, pw, wq, wp);
  hipLaunchKernelGGL(k_qkv,  dim3(768),  dim3(256), 0, stream, x, wq, qkvb, qbuf, kbuf, vbuf);
  hipLaunchKernelGGL(k_attn, dim3(1024), dim3(256), 0, stream, qbuf, kbuf, vbuf, biasb, ao);
  hipLaunchKernelGGL(k_proj, dim3(256),  dim3(256), 0, stream, ao, wp, pb, out);
}